// Round 12
// baseline (181.161 us; speedup 1.0000x reference)
//
#include <hip/hip_runtime.h>
#include <hip/hip_bf16.h>
#include <math.h>

// ---------------- problem constants ----------------
#define SEQ   524288          // 256*4*512 floats per sequence tensor
#define MROWS 1024            // 256*4 rows of 512
#define XDBL_P 557056         // 4*1024*136 per pair element

typedef __hip_bfloat16 bfloat;
typedef __bf16 bfx8 __attribute__((ext_vector_type(8)));
typedef float f32x4 __attribute__((ext_vector_type(4)));

__device__ __forceinline__ float gelu_tanh(float x){
    float x3 = x*x*x;
    float z = 0.7978845608028654f*(x + 0.044715f*x3);
    float az = fabsf(z);
    float e = __expf(-2.f*az);
    float th = copysignf((1.f - e)/(1.f + e), z);
    return 0.5f*x*(1.f + th);
}

__device__ __forceinline__ unsigned short bfbits(float x){
    union { __hip_bfloat16 h; unsigned short u; } cv;
    cv.h = __float2bfloat16(x);
    return cv.u;
}

__device__ __forceinline__ void glds16(const void* g, void* l){
    __builtin_amdgcn_global_load_lds(
        (const __attribute__((address_space(1))) unsigned int*)g,
        (__attribute__((address_space(3))) unsigned int*)l, 16, 0, 0);
}

#define VMWAIT(n) asm volatile("s_waitcnt vmcnt(" #n ")" ::: "memory")

__device__ __forceinline__ void ln_stats(const float* v, float& mean, float& rstd){
    float s = 0.f;
    #pragma unroll
    for (int t = 0; t < 8; ++t) s += v[t];
    #pragma unroll
    for (int off = 32; off > 0; off >>= 1) s += __shfl_xor(s, off, 64);
    mean = s * (1.f/512.f);
    float sq = 0.f;
    #pragma unroll
    for (int t = 0; t < 8; ++t){ float d = v[t] - mean; sq += d*d; }
    #pragma unroll
    for (int off = 32; off > 0; off >>= 1) sq += __shfl_xor(sq, off, 64);
    rstd = rsqrtf(sq * (1.f/512.f) + 1e-5f);
}

__device__ __forceinline__ int resize_taps(int o, float* w, int* j0_out){
    const float inv_scale = 18.0f/16.0f;
    float sf = (o + 0.5f)*inv_scale - 0.5f;
    int j0 = (int)ceilf(sf - inv_scale);
    int j1 = (int)floorf(sf + inv_scale);
    if (j0 < 0) j0 = 0;
    if (j1 > 17) j1 = 17;
    int n = j1 - j0 + 1;
    float sum = 0.f;
    for (int t = 0; t < n; ++t){
        float d = fabsf(sf - (float)(j0 + t)) * (16.0f/18.0f);
        float v = fmaxf(0.f, 1.f - d);
        w[t] = v; sum += v;
    }
    float r = 1.f / sum;
    for (int t = 0; t < n; ++t) w[t] *= r;
    *j0_out = j0;
    return n;
}

// ---------------- prep: cvt_w + to_seq3 + pool (R10 version) ----------------
struct CvtArgs {
    const float* s[6];
    bfloat* d[6];
    int c4[6];
};
__global__ void prep_kernel(CvtArgs a,
                            const float* __restrict__ style,
                            const float* __restrict__ content,
                            const float* __restrict__ pos_s,
                            float* __restrict__ s_seq, float* __restrict__ c_seq,
                            float* __restrict__ ps_seq,
                            bfloat* __restrict__ pooledT)
{
    __shared__ float tsh[32][33];
    int blk = blockIdx.x;
    int tid = threadIdx.x;
    if (blk < 5440){
        int i = blk*256 + tid;   // 5440*256 == 1392640 exactly
        int j = 0, base = 0;
        while (j < 5 && i >= a.c4[j]) { base = a.c4[j]; ++j; }
        int k = i - base;
        float4 v = ((const float4*)a.s[j])[k];
        union { bfloat h[4]; ushort4 u; } o;
        o.h[0] = __float2bfloat16(v.x); o.h[1] = __float2bfloat16(v.y);
        o.h[2] = __float2bfloat16(v.z); o.h[3] = __float2bfloat16(v.w);
        *(ushort4*)(a.d[j] + (size_t)k*4) = o.u;
    } else if (blk < 6976){
        int b2 = blk - 5440;     // [3][4][16][8]
        int lt = b2 & 7;  b2 >>= 3;
        int ct = b2 & 15; b2 >>= 4;
        int b  = b2 & 3;  b2 >>= 2;
        const float* in = b2==0 ? style : (b2==1 ? content : pos_s);
        float* o = b2==0 ? s_seq : (b2==1 ? c_seq : ps_seq);
        int c0 = ct*32, l0 = lt*32;
        int lx = tid & 31, g = tid >> 5;
        #pragma unroll
        for (int qq = 0; qq < 4; ++qq){
            int cy = g + qq*8;
            tsh[cy][lx] = in[(size_t)(b*512 + c0+cy)*256 + l0 + lx];
        }
        __syncthreads();
        #pragma unroll
        for (int qq = 0; qq < 4; ++qq){
            int ly = g + qq*8;
            o[((size_t)(l0+ly)*4 + b)*512 + c0 + lx] = tsh[lx][ly];
        }
    } else {
        int bij = blk - 6976;    // 1296
        int b = bij / 324;
        int ij = bij % 324;
        int i = ij / 18, jc = ij % 18;
        int s0 = (i*16)/18,  e0 = ((i+1)*16 + 17)/18;
        int s1 = (jc*16)/18, e1 = ((jc+1)*16 + 17)/18;
        float inv = 1.0f / (float)((e0-s0)*(e1-s1));
        for (int c = tid; c < 512; c += 256){
            float acc = 0.f;
            for (int h = s0; h < e0; ++h)
                for (int w = s1; w < e1; ++w)
                    acc += content[((b*512 + c)*16 + h)*16 + w];
            pooledT[(size_t)(b*324 + ij)*512 + c] = __float2bfloat16(acc * inv);
        }
    }
}

// pair LN at VSS entry: rows 0..2047, p=row>>10 picks (x,x2,weights[ibase+p])
__global__ __launch_bounds__(256) void ln_vss_pair_kernel(
    const float* __restrict__ x0, const float* __restrict__ x20,
    const float* __restrict__ x1, const float* __restrict__ x21,
    const float* __restrict__ wall, const float* __restrict__ ball,
    int ibase, bfloat* __restrict__ outb)
{
    int row = blockIdx.x*4 + (threadIdx.x >> 6);
    int lane = threadIdx.x & 63;
    int p = row >> 10, r2 = row & 1023;
    const float* in0 = (p ? x1 : x0) + (size_t)r2*512;
    const float* in1 = p ? x21 : x20;
    const float* w = wall + (ibase+p)*512;
    const float* b = ball + (ibase+p)*512;
    int base = lane*8;
    float v[8];
    #pragma unroll
    for (int t = 0; t < 8; ++t){
        v[t] = in0[base + t];
        if (in1) v[t] += in1[(size_t)r2*512 + base + t];
    }
    float mean, rstd;
    ln_stats(v, mean, rstd);
    bfloat* o = outb + (size_t)p*SEQ + (size_t)r2*512 + base;
    union { ushort u[8]; uint4 q; } pk;
    #pragma unroll
    for (int t = 0; t < 8; ++t)
        pk.u[t] = bfbits((v[t] - mean)*rstd*w[base + t] + b[base + t]);
    *(uint4*)o = pk.q;
}

// tgt = LN(a0+a1; w1,b1) + LN(c0+c1; w2,b2); fp32 + bf16 out
__global__ __launch_bounds__(256) void dn_pair_kernel(
    const float* __restrict__ a0, const float* __restrict__ a1,
    const float* __restrict__ w1, const float* __restrict__ b1,
    const float* __restrict__ c0, const float* __restrict__ c1,
    const float* __restrict__ w2, const float* __restrict__ b2,
    float* __restrict__ outf, bfloat* __restrict__ outb)
{
    int row = blockIdx.x*4 + (threadIdx.x >> 6);
    int lane = threadIdx.x & 63;
    int base = lane*8;
    size_t ro = (size_t)row*512 + base;
    float va[8], vc[8];
    #pragma unroll
    for (int t = 0; t < 8; ++t){ va[t] = a0[ro+t] + a1[ro+t]; vc[t] = c0[ro+t] + c1[ro+t]; }
    float m1, r1, m2, r2;
    ln_stats(va, m1, r1);
    ln_stats(vc, m2, r2);
    union { ushort u[8]; uint4 q; } pk;
    #pragma unroll
    for (int t = 0; t < 8; ++t){
        float o = (va[t]-m1)*r1*w1[base+t] + b1[base+t]
                + (vc[t]-m2)*r2*w2[base+t] + b2[base+t];
        outf[ro + t] = o;
        pk.u[t] = bfbits(o);
    }
    *(uint4*)(outb + ro) = pk.q;
}

// double-LN + transposed store to output
__global__ __launch_bounds__(256) void ln2_out_kernel(
    const float* __restrict__ in0, const float* __restrict__ in1,
    const float* __restrict__ w1, const float* __restrict__ b1,
    const float* __restrict__ w2, const float* __restrict__ b2,
    float* __restrict__ out)
{
    int row = blockIdx.x*4 + (threadIdx.x >> 6);
    int lane = threadIdx.x & 63;
    int base = lane*8;
    size_t ro = (size_t)row*512 + base;
    float v[8];
    #pragma unroll
    for (int t = 0; t < 8; ++t) v[t] = in0[ro+t] + in1[ro+t];
    float mean, rstd;
    ln_stats(v, mean, rstd);
    #pragma unroll
    for (int t = 0; t < 8; ++t) v[t] = (v[t]-mean)*rstd*w1[base+t] + b1[base+t];
    ln_stats(v, mean, rstd);
    int l = row >> 2, b = row & 3;
    #pragma unroll
    for (int t = 0; t < 8; ++t){
        float o = (v[t]-mean)*rstd*w2[base+t] + b2[base+t];
        out[(size_t)(b*512 + base + t)*256 + l] = o;
    }
}

// ---------------- bf16 MFMA GEMM, heterogeneous multi-job ----------
struct GJob {
    const bfloat* A; const bfloat* W;
    const float* bias; const float* res1; const float* res2;
    float* Cf; bfloat* Cb;
    const float* cw; const float* cb;   // epi==2 conv
    bfloat* vb;                         // epi==2 bf16 out
    int arev, M, N, K, nbn, nblk, epi;  // epi: 0 plain 1 gelu 2 conv 3 xproj 4 resize
};
struct GBatch { GJob j[5]; int cum[5]; int nj; };

__global__ __launch_bounds__(256) void gemm_multi_kernel(GBatch B)
{
    __shared__ __align__(16) char lds[65536];
    int bi = blockIdx.x;
    int ji = 0, start = 0;
    while (ji < B.nj - 1 && bi >= B.cum[ji]){ start = B.cum[ji]; ++ji; }
    GJob j = B.j[ji];
    int wgid0 = bi - start;
    const int tid = threadIdx.x;

    if (j.epi == 4){
        // resize job: 64 blocks x 16 positions; res1 = pc18T src
        #pragma unroll
        for (int qq = 0; qq < 16; ++qq){
            int pos = wgid0*16 + qq;
            int b = pos >> 8;
            int y = (pos >> 4) & 15, x = pos & 15;
            float wy[3], wx[3];
            int jy0, jx0;
            int ny = resize_taps(y, wy, &jy0);
            int nx = resize_taps(x, wx, &jx0);
            const float* src = j.res1;
            for (int c = tid; c < 512; c += 256){
                float acc = 0.f;
                for (int ty = 0; ty < ny; ++ty)
                    for (int tx = 0; tx < nx; ++tx)
                        acc += wy[ty]*wx[tx] *
                               src[(size_t)(b*324 + (jy0+ty)*18 + (jx0+tx))*512 + c];
                j.Cf[(size_t)((y*16 + x)*4 + b)*512 + c] = acc;
            }
        }
        return;
    }

    const int M = j.M, N = j.N, K = j.K, nbn = j.nbn;
    // bijective XCD swizzle (m204)
    int nwg = j.nblk;
    int q = nwg >> 3, r = nwg & 7;
    int xcd = wgid0 & 7, off = wgid0 >> 3;
    int wgid = (xcd < r ? xcd*(q+1) : r*(q+1) + (xcd-r)*q) + off;
    int bm = (wgid / nbn) * 64;
    int bn = (wgid % nbn) * 64;

    const int wv = tid >> 6, ln = tid & 63;
    const int r0 = tid >> 3;
    const int cs = (tid & 7) ^ (r0 & 7);
    int ar0 = bm + r0;       if (ar0 > M-1) ar0 = M-1;
    int ar1 = bm + r0 + 32;  if (ar1 > M-1) ar1 = M-1;
    if (j.arev){ ar0 = (ar0 & ~3) | (3 - (ar0 & 3)); ar1 = (ar1 & ~3) | (3 - (ar1 & 3)); }
    int br0 = bn + r0;       if (br0 > N-1) br0 = N-1;
    int br1 = bn + r0 + 32;  if (br1 > N-1) br1 = N-1;
    const bfloat* a0p = j.A + (size_t)ar0*K + cs*8;
    const bfloat* a1p = j.A + (size_t)ar1*K + cs*8;
    const bfloat* b0p = j.W + (size_t)br0*K + cs*8;
    const bfloat* b1p = j.W + (size_t)br1*K + cs*8;

    auto STAGE = [&](int bb, int k0){
        char* base = lds + bb*16384 + wv*1024;
        glds16(a0p + k0, base);
        glds16(a1p + k0, base + 4096);
        glds16(b0p + k0, base + 8192);
        glds16(b1p + k0, base + 12288);
    };

    const int wr = wv >> 1, wc = wv & 1;
    const int fr = ln & 15, fc = ln >> 4;
    f32x4 acc[2][2] = {};

    auto COMP = [&](int bb){
        char* bA = lds + bb*16384;
        char* bB = bA + 8192;
        int ra0 = wr*32 + fr, ra1 = ra0 + 16;
        int rb0 = wc*32 + fr, rb1 = rb0 + 16;
        #pragma unroll
        for (int kk = 0; kk < 2; ++kk){
            int ch = kk*4 + fc;
            bfx8 a0 = *(const bfx8*)(bA + ra0*128 + ((ch ^ (ra0&7))<<4));
            bfx8 a1 = *(const bfx8*)(bA + ra1*128 + ((ch ^ (ra1&7))<<4));
            bfx8 b0 = *(const bfx8*)(bB + rb0*128 + ((ch ^ (rb0&7))<<4));
            bfx8 b1 = *(const bfx8*)(bB + rb1*128 + ((ch ^ (rb1&7))<<4));
            acc[0][0] = __builtin_amdgcn_mfma_f32_16x16x32_bf16(a0,b0,acc[0][0],0,0,0);
            acc[0][1] = __builtin_amdgcn_mfma_f32_16x16x32_bf16(a0,b1,acc[0][1],0,0,0);
            acc[1][0] = __builtin_amdgcn_mfma_f32_16x16x32_bf16(a1,b0,acc[1][0],0,0,0);
            acc[1][1] = __builtin_amdgcn_mfma_f32_16x16x32_bf16(a1,b1,acc[1][1],0,0,0);
        }
    };

    const int nt = K >> 6;
    for (int s = 0; s < 3 && s < nt; ++s) STAGE(s, s << 6);
    for (int t = 0; t < nt; ++t){
        int rem = nt - 1 - t;
        if (rem >= 2)      VMWAIT(8);
        else if (rem == 1) VMWAIT(4);
        else               VMWAIT(0);
        __builtin_amdgcn_sched_barrier(0);
        __builtin_amdgcn_s_barrier();
        if (t + 3 < nt) STAGE((t+3) & 3, (t+3) << 6);
        COMP(t & 3);
    }

    const int er = (ln >> 4) * 4;
    const int ec = ln & 15;

    if (j.epi == 2){
        __syncthreads();
        float* ut = (float*)lds;
        #pragma unroll
        for (int i = 0; i < 2; ++i)
        #pragma unroll
        for (int jj = 0; jj < 2; ++jj)
        #pragma unroll
        for (int rr = 0; rr < 4; ++rr){
            int ml = wr*32 + i*16 + er + rr;
            int nl = wc*32 + jj*16 + ec;
            ut[ml*65 + nl] = acc[i][jj][rr] + j.bias[bn + nl];
        }
        __syncthreads();
        int rrow = tid >> 2, c0 = (tid & 3) * 16;
        int bt4 = rrow & ~3, lv = rrow & 3;
        int m = bm + rrow;
        float g[16];
        #pragma unroll
        for (int c = 0; c < 16; ++c){
            int n = bn + c0 + c;
            float a = j.cb[n];
            #pragma unroll
            for (int kh = 0; kh < 3; ++kh){
                int hh = lv + kh - 1;
                if (hh >= 0 && hh < 4)
                    a += ut[(bt4 + hh)*65 + c0 + c] * j.cw[(n*3 + kh)*3 + 1];
            }
            g[c] = gelu_tanh(a);
        }
        union { ushort u[8]; uint4 qv; } pk;
        #pragma unroll
        for (int h = 0; h < 2; ++h){
            #pragma unroll
            for (int t = 0; t < 8; ++t) pk.u[t] = bfbits(g[h*8 + t]);
            *(uint4*)(j.vb + (size_t)m*512 + bn + c0 + h*8) = pk.qv;
        }
        return;
    }

    #pragma unroll
    for (int i = 0; i < 2; ++i)
    #pragma unroll
    for (int jj = 0; jj < 2; ++jj)
    #pragma unroll
    for (int rr = 0; rr < 4; ++rr){
        int m = bm + wr*32 + i*16 + er + rr;
        int n = bn + wc*32 + jj*16 + ec;
        if (m >= M || n >= N) continue;
        float v = acc[i][jj][rr];
        if (j.bias) v += j.bias[n];
        if (j.epi == 1) v = gelu_tanh(v);
        if (j.res1) v += j.res1[(size_t)m*N + n];
        if (j.res2) v += j.res2[(size_t)m*N + n];
        if (j.epi == 3){
            int k2 = n >= 136;
            int cc = n - (k2 ? 136 : 0);
            j.Cf[((size_t)(k2*1024 + m))*136 + cc] = v;
        } else {
            if (j.Cf) j.Cf[(size_t)m*N + n] = v;
            if (j.Cb) j.Cb[(size_t)m*N + n] = __float2bfloat16(v);
        }
    }
}

// ---------------- fused selective scan + combine + LN (bf16 x input) ---------
__global__ __launch_bounds__(256) void scan_fused_kernel(
    const float* __restrict__ xdbl,
    const bfloat* __restrict__ vb,
    const float* __restrict__ dt_bias,
    const float* __restrict__ A_log,
    const float* __restrict__ Dp,
    const float* __restrict__ von_w, const float* __restrict__ von_b,
    int ibase, bfloat* __restrict__ outb)
{
    __shared__ float yb[4][4][512];
    int blk = blockIdx.x;
    int p = blk >> 8, bt = blk & 255;
    int k = threadIdx.x >> 6, lane = threadIdx.x & 63;

    const float* xd = xdbl + (size_t)p*XDBL_P + (size_t)(k*1024 + bt*4)*136;

    float bb[4], cc[4];
    #pragma unroll
    for (int l = 0; l < 4; ++l){
        bb[l] = xd[l*136 + 8 + lane];
        cc[l] = xd[l*136 + 72 + lane];
    }

    int sl = (lane & 31) >> 3, snh = lane & 7;
    float Aval = -expf(A_log[p*32 + k*8 + snh]);
    float draw = xd[sl*136 + snh] + dt_bias[p*32 + k*8 + snh];
    float dtv = fmaxf(draw, 0.f) + log1pf(expf(-fabsf(draw)));
    float dAv = expf(dtv * Aval);

    float s[16];
    #pragma unroll
    for (int l = 0; l < 4; ++l)
    #pragma unroll
    for (int jj = 0; jj < 4; ++jj)
        s[l*4+jj] = cc[l]*bb[jj];
    #pragma unroll
    for (int off = 32; off > 0; off >>= 1)
        #pragma unroll
        for (int i = 0; i < 16; ++i)
            s[i] += __shfl_xor(s[i], off, 64);

    float x[4][8];
    #pragma unroll
    for (int lp = 0; lp < 4; ++lp){
        int row = bt*4 + ((k < 2) ? lp : 3 - lp);
        const bfloat* xr = vb + (size_t)p*SEQ + (size_t)row*512 + lane;
        #pragma unroll
        for (int nh = 0; nh < 8; ++nh) x[lp][nh] = __bfloat162float(xr[nh*64]);
    }

    #pragma unroll
    for (int nh = 0; nh < 8; ++nh){
        float dtl[4], dal[4];
        #pragma unroll
        for (int l = 0; l < 4; ++l){
            dtl[l] = __shfl(dtv, l*8 + nh, 64);
            dal[l] = __shfl(dAv, l*8 + nh, 64);
        }
        float Dv = Dp[p*32 + k*8 + nh];
        float coef[4] = {0.f, 0.f, 0.f, 0.f};
        #pragma unroll
        for (int l = 0; l < 4; ++l){
            #pragma unroll
            for (int jj = 0; jj < 4; ++jj) coef[jj] *= dal[l];
            coef[l] = dtl[l];
            float y = Dv * x[l][nh];
            #pragma unroll
            for (int jj = 0; jj <= l; ++jj) y += coef[jj]*s[l*4+jj]*x[jj][nh];
            yb[k][l][nh*64 + lane] = y;
        }
    }
    __syncthreads();

    int l = k, rl = 3 - k;
    int base = lane*8;
    float vv[8];
    #pragma unroll
    for (int t = 0; t < 8; ++t)
        vv[t] = yb[0][l][base+t] + yb[1][l][base+t]
              + yb[2][rl][base+t] + yb[3][rl][base+t];
    float mean, rstd;
    ln_stats(vv, mean, rstd);
    const float* w = von_w + (ibase+p)*512;
    const float* bv = von_b + (ibase+p)*512;
    union { ushort u[8]; uint4 qv; } pk;
    #pragma unroll
    for (int t = 0; t < 8; ++t)
        pk.u[t] = bfbits((vv[t]-mean)*rstd*w[base+t] + bv[base+t]);
    *(uint4*)(outb + (size_t)p*SEQ + (size_t)(bt*4 + l)*512 + base) = pk.qv;
}

extern "C" void kernel_launch(void* const* d_in, const int* in_sizes, int n_in,
                              void* d_out, int out_size, void* d_ws, size_t ws_size,
                              hipStream_t stream)
{
    const float* style   = (const float*)d_in[0];
    const float* content = (const float*)d_in[2];
    const float* pos_s   = (const float*)d_in[4];
    const float* newps_w = (const float*)d_in[5];
    const float* newps_b = (const float*)d_in[6];
    const float* vln_w   = (const float*)d_in[7];
    const float* vln_b   = (const float*)d_in[8];
    const float* vin_b   = (const float*)d_in[10];
    const float* vconv_w = (const float*)d_in[11];
    const float* vconv_b = (const float*)d_in[12];
    const float* vdt_bias= (const float*)d_in[14];
    const float* vA_log  = (const float*)d_in[15];
    const float* vD      = (const float*)d_in[16];
    const float* von_w   = (const float*)d_in[17];
    const float* von_b   = (const float*)d_in[18];
    const float* vout_b  = (const float*)d_in[20];
    const float* lin1_b  = (const float*)d_in[22];
    const float* lin2_b  = (const float*)d_in[24];
    const float* dn1_w   = (const float*)d_in[25];
    const float* dn1_b   = (const float*)d_in[26];
    const float* dn2_w   = (const float*)d_in[27];
    const float* dn2_b   = (const float*)d_in[28];
    const float* dn3_w   = (const float*)d_in[29];
    const float* dn3_b   = (const float*)d_in[30];
    const float* decn_w  = (const float*)d_in[31];
    const float* decn_b  = (const float*)d_in[32];

    float* out = (float*)d_out;
    float* ws  = (float*)d_ws;

    // ---- fp32 region ----
    float* s_seq  = ws + (size_t) 0*SEQ;
    float* c_seq  = ws + (size_t) 1*SEQ;
    float* ps_seq = ws + (size_t) 2*SEQ;
    float* pc_seq = ws + (size_t) 3*SEQ;
    float* s_enc  = ws + (size_t) 4*SEQ;
    float* c_enc  = ws + (size_t) 5*SEQ;
    float* t1     = ws + (size_t) 6*SEQ;
    float* t2     = ws + (size_t) 7*SEQ;
    float* tgt    = ws + (size_t) 8*SEQ;
    float* ffnout = ws + (size_t) 9*SEQ;
    float* xdbl   = ws + (size_t)10*SEQ;   // [2][557056] spans 10-12
    float* pc18T  = ws + (size_t)13*SEQ;   // 663552 floats (13-14)

    // ---- bf16 region at 15 SEQ floats ----
    bfloat* wb = (bfloat*)(ws + (size_t)15*SEQ);
    bfloat* wb_vin    = wb;
    bfloat* wb_xproj  = wb + 1048576;
    bfloat* wb_vout   = wb + 2162688;
    bfloat* wb_lin1   = wb + 3211264;
    bfloat* wb_lin2   = wb + 4259840;
    bfloat* wb_newps  = wb + 5308416;
    bfloat* xn_bf     = wb + 5570560;               // [2][SEQ] (also yln pair)
    bfloat* vbuf_bf   = xn_bf   + (size_t)2*SEQ;    // [2][SEQ]
    bfloat* tgt_bf    = vbuf_bf + (size_t)2*SEQ;    // SEQ
    bfloat* ffn_bf    = tgt_bf  + (size_t)SEQ;      // 1024*2048
    bfloat* pooled_bf = ffn_bf;                     // pre-VSS only

    GJob Z = {};

    auto mk = [&](const bfloat* A, const bfloat* W, const float* bias,
                  const float* r1, const float* r2, float* Cf, bfloat* Cb,
                  int M, int N, int K, int epi, int arev)->GJob{
        GJob g = Z;
        g.A = A; g.W = W; g.bias = bias; g.res1 = r1; g.res2 = r2;
        g.Cf = Cf; g.Cb = Cb; g.M = M; g.N = N; g.K = K;
        g.nbn = (N + 63)/64; g.nblk = ((M + 63)/64) * g.nbn;
        g.epi = epi; g.arev = arev;
        return g;
    };

    auto launch_multi = [&](GJob* jobs, int nj){
        GBatch B;
        int cum = 0;
        for (int i = 0; i < nj; ++i){
            B.j[i] = jobs[i];
            cum += jobs[i].nblk;
            B.cum[i] = cum;
        }
        B.nj = nj;
        gemm_multi_kernel<<<cum, 256, 0, stream>>>(B);
    };

    // ---- 1: prep (cvt + to_seq3 + pool) ----
    CvtArgs ca;
    ca.s[0]=(const float*)d_in[9];  ca.d[0]=wb_vin;
    ca.s[1]=(const float*)d_in[13]; ca.d[1]=wb_xproj;
    ca.s[2]=(const float*)d_in[19]; ca.d[2]=wb_vout;
    ca.s[3]=(const float*)d_in[21]; ca.d[3]=wb_lin1;
    ca.s[4]=(const float*)d_in[23]; ca.d[4]=wb_lin2;
    ca.s[5]=newps_w;                ca.d[5]=wb_newps;
    ca.c4[0]=262144; ca.c4[1]=540672; ca.c4[2]=802816;
    ca.c4[3]=1064960; ca.c4[4]=1327104; ca.c4[5]=1392640;
    prep_kernel<<<8272, 256, 0, stream>>>(ca, style, content, pos_s,
                                          s_seq, c_seq, ps_seq, pooled_bf);

    // ---- VSS pair (mid+tail); newps folded into enc vin batch, resize into
    //      enc xproj batch ----
    auto vss_pair = [&](int ibase, const float* xa, const float* x2a,
                        const float* xb, const float* x2b,
                        float* oa, float* ob, int enc){
        ln_vss_pair_kernel<<<512, 256, 0, stream>>>(xa, x2a, xb, x2b,
                                                    vln_w, vln_b, ibase, xn_bf);
        // vin+conv (+ newps when enc)
        GJob jv[3];
        for (int p = 0; p < 2; ++p){
            int i = ibase + p;
            jv[p] = mk(xn_bf + (size_t)p*SEQ, wb_vin + (size_t)i*262144,
                       vin_b + i*512, nullptr, nullptr, nullptr, nullptr,
                       MROWS, 512, 512, 2, 0);
            jv[p].cw = vconv_w + (size_t)i*4608;
            jv[p].cb = vconv_b + i*512;
            jv[p].vb = vbuf_bf + (size_t)p*SEQ;
        }
        int nvj = 2;
        if (enc){
            jv[2] = mk(pooled_bf, wb_newps, newps_b, nullptr, nullptr,
                       pc18T, nullptr, 1296, 512, 512, 0, 0);
            nvj = 3;
        }
        launch_multi(jv, nvj);

        // xproj (+ resize when enc)
        GJob jx[5];
        for (int zz = 0; zz < 4; ++zz){
            int p = zz >> 1, rev = zz & 1, i = ibase + p;
            jx[zz] = mk(vbuf_bf + (size_t)p*SEQ,
                        wb_xproj + (size_t)i*278528 + (size_t)rev*272*512,
                        nullptr, nullptr, nullptr,
                        xdbl + (size_t)p*XDBL_P + (size_t)rev*278528, nullptr,
                        MROWS, 272, 512, 3, rev);
        }
        int nxj = 4;
        if (enc){
            jx[4] = Z;
            jx[4].epi = 4; jx[4].nblk = 64;
            jx[4].res1 = pc18T; jx[4].Cf = pc_seq;
            nxj = 5;
        }
        launch_multi(jx, nxj);

        scan_fused_kernel<<<512, 256, 0, stream>>>(xdbl, vbuf_bf,
                                                   vdt_bias + ibase*32,
                                                   vA_log + ibase*32,
                                                   vD + ibase*32,
                                                   von_w, von_b, ibase, xn_bf);

        GJob jo[2];
        const float* r1[2] = {xa, xb};
        const float* r2[2] = {x2a, x2b};
        float* oo[2] = {oa, ob};
        for (int p = 0; p < 2; ++p){
            int i = ibase + p;
            jo[p] = mk(xn_bf + (size_t)p*SEQ, wb_vout + (size_t)i*262144,
                       vout_b + i*512, r1[p], r2[p], oo[p], nullptr,
                       MROWS, 512, 512, 0, 0);
        }
        launch_multi(jo, 2);
    };

    // ---- encoders (newps/resize ride along) ----
    vss_pair(0, s_seq, nullptr, c_seq, nullptr, s_enc, c_enc, 1);

    // ---- decoders ----
    vss_pair(2, c_enc, pc_seq, s_enc, ps_seq, t1, t2, 0);

    dn_pair_kernel<<<256, 256, 0, stream>>>(c_enc, t1, dn1_w, dn1_b,
                                            s_enc, t2, dn2_w, dn2_b,
                                            tgt, tgt_bf);

    // ---- FFN + tail ----
    GJob jf = mk(tgt_bf, wb_lin1, lin1_b, nullptr, nullptr,
                 nullptr, ffn_bf, MROWS, 2048, 512, 1, 0);
    launch_multi(&jf, 1);
    GJob jg = mk(ffn_bf, wb_lin2, lin2_b, nullptr, nullptr,
                 ffnout, nullptr, MROWS, 512, 2048, 0, 0);
    launch_multi(&jg, 1);
    ln2_out_kernel<<<256, 256, 0, stream>>>(tgt, ffnout, dn3_w, dn3_b,
                                            decn_w, decn_b, out);
}

// Round 13
// 165.739 us; speedup vs baseline: 1.0930x; 1.0930x over previous
//
#include <hip/hip_runtime.h>
#include <hip/hip_bf16.h>
#include <math.h>

// ---------------- problem constants ----------------
#define SEQ   524288          // 256*4*512 floats per sequence tensor
#define MROWS 1024            // 256*4 rows of 512
#define XDBL_P 557056         // 4*1024*136 per pair element

typedef __hip_bfloat16 bfloat;
typedef __bf16 bfx8 __attribute__((ext_vector_type(8)));
typedef float f32x4 __attribute__((ext_vector_type(4)));

// fast tanh-gelu via v_exp_f32 (jax.nn.gelu approximate=True)
__device__ __forceinline__ float gelu_tanh(float x){
    float x3 = x*x*x;
    float z = 0.7978845608028654f*(x + 0.044715f*x3);
    float az = fabsf(z);
    float e = __expf(-2.f*az);
    float th = copysignf((1.f - e)/(1.f + e), z);
    return 0.5f*x*(1.f + th);
}

__device__ __forceinline__ unsigned short bfbits(float x){
    union { __hip_bfloat16 h; unsigned short u; } cv;
    cv.h = __float2bfloat16(x);
    return cv.u;
}

__device__ __forceinline__ void glds16(const void* g, void* l){
    __builtin_amdgcn_global_load_lds(
        (const __attribute__((address_space(1))) unsigned int*)g,
        (__attribute__((address_space(3))) unsigned int*)l, 16, 0, 0);
}

#define VMWAIT(n) asm volatile("s_waitcnt vmcnt(" #n ")" ::: "memory")

__device__ __forceinline__ void ln_stats(const float* v, float& mean, float& rstd){
    float s = 0.f;
    #pragma unroll
    for (int t = 0; t < 8; ++t) s += v[t];
    #pragma unroll
    for (int off = 32; off > 0; off >>= 1) s += __shfl_xor(s, off, 64);
    mean = s * (1.f/512.f);
    float sq = 0.f;
    #pragma unroll
    for (int t = 0; t < 8; ++t){ float d = v[t] - mean; sq += d*d; }
    #pragma unroll
    for (int off = 32; off > 0; off >>= 1) sq += __shfl_xor(sq, off, 64);
    rstd = rsqrtf(sq * (1.f/512.f) + 1e-5f);
}

// ---------------- prep: cvt_w + to_seq3 + pool in one kernel ----------------
struct CvtArgs {
    const float* s[6];
    bfloat* d[6];
    int c4[6];
};
__global__ void prep_kernel(CvtArgs a,
                            const float* __restrict__ style,
                            const float* __restrict__ content,
                            const float* __restrict__ pos_s,
                            float* __restrict__ s_seq, float* __restrict__ c_seq,
                            float* __restrict__ ps_seq,
                            bfloat* __restrict__ pooledT)
{
    __shared__ float tsh[32][33];
    int blk = blockIdx.x;
    int tid = threadIdx.x;
    if (blk < 5440){
        int i = blk*256 + tid;   // 5440*256 == 1392640 exactly
        int j = 0, base = 0;
        while (j < 5 && i >= a.c4[j]) { base = a.c4[j]; ++j; }
        int k = i - base;
        float4 v = ((const float4*)a.s[j])[k];
        union { bfloat h[4]; ushort4 u; } o;
        o.h[0] = __float2bfloat16(v.x); o.h[1] = __float2bfloat16(v.y);
        o.h[2] = __float2bfloat16(v.z); o.h[3] = __float2bfloat16(v.w);
        *(ushort4*)(a.d[j] + (size_t)k*4) = o.u;
    } else if (blk < 6976){
        int b2 = blk - 5440;     // [3][4][16][8]
        int lt = b2 & 7;  b2 >>= 3;
        int ct = b2 & 15; b2 >>= 4;
        int b  = b2 & 3;  b2 >>= 2;
        const float* in = b2==0 ? style : (b2==1 ? content : pos_s);
        float* o = b2==0 ? s_seq : (b2==1 ? c_seq : ps_seq);
        int c0 = ct*32, l0 = lt*32;
        int lx = tid & 31, g = tid >> 5;
        #pragma unroll
        for (int qq = 0; qq < 4; ++qq){
            int cy = g + qq*8;
            tsh[cy][lx] = in[(size_t)(b*512 + c0+cy)*256 + l0 + lx];
        }
        __syncthreads();
        #pragma unroll
        for (int qq = 0; qq < 4; ++qq){
            int ly = g + qq*8;
            o[((size_t)(l0+ly)*4 + b)*512 + c0 + lx] = tsh[lx][ly];
        }
    } else {
        int bij = blk - 6976;    // 1296
        int b = bij / 324;
        int ij = bij % 324;
        int i = ij / 18, jc = ij % 18;
        int s0 = (i*16)/18,  e0 = ((i+1)*16 + 17)/18;
        int s1 = (jc*16)/18, e1 = ((jc+1)*16 + 17)/18;
        float inv = 1.0f / (float)((e0-s0)*(e1-s1));
        for (int c = tid; c < 512; c += 256){
            float acc = 0.f;
            for (int h = s0; h < e0; ++h)
                for (int w = s1; w < e1; ++w)
                    acc += content[((b*512 + c)*16 + h)*16 + w];
            pooledT[(size_t)(b*324 + ij)*512 + c] = __float2bfloat16(acc * inv);
        }
    }
}

__device__ __forceinline__ int resize_taps(int o, float* w, int* j0_out){
    const float inv_scale = 18.0f/16.0f;
    float sf = (o + 0.5f)*inv_scale - 0.5f;
    int j0 = (int)ceilf(sf - inv_scale);
    int j1 = (int)floorf(sf + inv_scale);
    if (j0 < 0) j0 = 0;
    if (j1 > 17) j1 = 17;
    int n = j1 - j0 + 1;
    float sum = 0.f;
    for (int t = 0; t < n; ++t){
        float d = fabsf(sf - (float)(j0 + t)) * (16.0f/18.0f);
        float v = fmaxf(0.f, 1.f - d);
        w[t] = v; sum += v;
    }
    float r = 1.f / sum;
    for (int t = 0; t < n; ++t) w[t] *= r;
    *j0_out = j0;
    return n;
}

__global__ void resize_kernel(const float* __restrict__ pc18T, float* __restrict__ pc_seq){
    int bid = blockIdx.x;
    int b = bid >> 8;
    int yx = bid & 255;
    int y = yx >> 4, x = yx & 15;
    float wy[3], wx[3];
    int jy0, jx0;
    int ny = resize_taps(y, wy, &jy0);
    int nx = resize_taps(x, wx, &jx0);
    for (int c = threadIdx.x; c < 512; c += 256){
        float acc = 0.f;
        for (int ty = 0; ty < ny; ++ty)
            for (int tx = 0; tx < nx; ++tx)
                acc += wy[ty]*wx[tx] *
                       pc18T[(size_t)(b*324 + (jy0+ty)*18 + (jx0+tx))*512 + c];
        pc_seq[(size_t)((y*16 + x)*4 + b)*512 + c] = acc;
    }
}

// pair LN at VSS entry: rows 0..2047, p=row>>10 picks (x,x2,weights[ibase+p])
__global__ __launch_bounds__(256) void ln_vss_pair_kernel(
    const float* __restrict__ x0, const float* __restrict__ x20,
    const float* __restrict__ x1, const float* __restrict__ x21,
    const float* __restrict__ wall, const float* __restrict__ ball,
    int ibase, bfloat* __restrict__ outb)
{
    int row = blockIdx.x*4 + (threadIdx.x >> 6);
    int lane = threadIdx.x & 63;
    int p = row >> 10, r2 = row & 1023;
    const float* in0 = (p ? x1 : x0) + (size_t)r2*512;
    const float* in1 = p ? x21 : x20;
    const float* w = wall + (ibase+p)*512;
    const float* b = ball + (ibase+p)*512;
    int base = lane*8;
    float v[8];
    #pragma unroll
    for (int t = 0; t < 8; ++t){
        v[t] = in0[base + t];
        if (in1) v[t] += in1[(size_t)r2*512 + base + t];
    }
    float mean, rstd;
    ln_stats(v, mean, rstd);
    bfloat* o = outb + (size_t)p*SEQ + (size_t)r2*512 + base;
    union { ushort u[8]; uint4 q; } pk;
    #pragma unroll
    for (int t = 0; t < 8; ++t)
        pk.u[t] = bfbits((v[t] - mean)*rstd*w[base + t] + b[base + t]);
    *(uint4*)o = pk.q;
}

// tgt = LN(a0+a1; w1,b1) + LN(c0+c1; w2,b2); fp32 + bf16 out
__global__ __launch_bounds__(256) void dn_pair_kernel(
    const float* __restrict__ a0, const float* __restrict__ a1,
    const float* __restrict__ w1, const float* __restrict__ b1,
    const float* __restrict__ c0, const float* __restrict__ c1,
    const float* __restrict__ w2, const float* __restrict__ b2,
    float* __restrict__ outf, bfloat* __restrict__ outb)
{
    int row = blockIdx.x*4 + (threadIdx.x >> 6);
    int lane = threadIdx.x & 63;
    int base = lane*8;
    size_t ro = (size_t)row*512 + base;
    float va[8], vc[8];
    #pragma unroll
    for (int t = 0; t < 8; ++t){ va[t] = a0[ro+t] + a1[ro+t]; vc[t] = c0[ro+t] + c1[ro+t]; }
    float m1, r1, m2, r2;
    ln_stats(va, m1, r1);
    ln_stats(vc, m2, r2);
    union { ushort u[8]; uint4 q; } pk;
    #pragma unroll
    for (int t = 0; t < 8; ++t){
        float o = (va[t]-m1)*r1*w1[base+t] + b1[base+t]
                + (vc[t]-m2)*r2*w2[base+t] + b2[base+t];
        outf[ro + t] = o;
        pk.u[t] = bfbits(o);
    }
    *(uint4*)(outb + ro) = pk.q;
}

// double-LN + transposed store to output
__global__ __launch_bounds__(256) void ln2_out_kernel(
    const float* __restrict__ in0, const float* __restrict__ in1,
    const float* __restrict__ w1, const float* __restrict__ b1,
    const float* __restrict__ w2, const float* __restrict__ b2,
    float* __restrict__ out)
{
    int row = blockIdx.x*4 + (threadIdx.x >> 6);
    int lane = threadIdx.x & 63;
    int base = lane*8;
    size_t ro = (size_t)row*512 + base;
    float v[8];
    #pragma unroll
    for (int t = 0; t < 8; ++t) v[t] = in0[ro+t] + in1[ro+t];
    float mean, rstd;
    ln_stats(v, mean, rstd);
    #pragma unroll
    for (int t = 0; t < 8; ++t) v[t] = (v[t]-mean)*rstd*w1[base+t] + b1[base+t];
    ln_stats(v, mean, rstd);
    int l = row >> 2, b = row & 3;
    #pragma unroll
    for (int t = 0; t < 8; ++t){
        float o = (v[t]-mean)*rstd*w2[base+t] + b2[base+t];
        out[(size_t)(b*512 + base + t)*256 + l] = o;
    }
}

// ---------------- bf16 MFMA GEMM, multi-job, counted-vmcnt pipeline ----------
struct GJob {
    const bfloat* A; const bfloat* W;
    const float* bias; const float* res1; const float* res2;
    float* Cf; bfloat* Cb;
    const float* cw; const float* cb;   // epi==2 conv
    bfloat* vb;                         // epi==2 bf16 out
    int arev;                           // permute A rows within groups of 4
};

// epi: 0 plain, 1 gelu, 2 conv+gelu bf16-out (M=1024,N=512), 3 xproj scatter (N=272)
// 4 LDS bufs x 16KB, 3-deep prefetch, s_waitcnt vmcnt(8) steady state,
// raw s_barrier (never drains the load queue in the main loop).
__global__ __launch_bounds__(256) void gemm3_kernel(
    GJob J0, GJob J1, GJob J2, GJob J3,
    int M, int N, int K, int nbn, int epi)
{
    __shared__ __align__(16) char lds[65536];
    const int z = blockIdx.z;
    GJob j = (z==0) ? J0 : (z==1) ? J1 : (z==2) ? J2 : J3;

    // bijective XCD swizzle (m204)
    int nwg = gridDim.x;
    int orig = blockIdx.x;
    int q = nwg >> 3, r = nwg & 7;
    int xcd = orig & 7, off = orig >> 3;
    int wgid = (xcd < r ? xcd*(q+1) : r*(q+1) + (xcd-r)*q) + off;
    int bm = (wgid / nbn) * 64;
    int bn = (wgid % nbn) * 64;

    const int tid = threadIdx.x;
    const int wv = tid >> 6, ln = tid & 63;

    const int r0 = tid >> 3;
    const int cs = (tid & 7) ^ (r0 & 7);
    int ar0 = bm + r0;       if (ar0 > M-1) ar0 = M-1;
    int ar1 = bm + r0 + 32;  if (ar1 > M-1) ar1 = M-1;
    if (j.arev){ ar0 = (ar0 & ~3) | (3 - (ar0 & 3)); ar1 = (ar1 & ~3) | (3 - (ar1 & 3)); }
    int br0 = bn + r0;       if (br0 > N-1) br0 = N-1;
    int br1 = bn + r0 + 32;  if (br1 > N-1) br1 = N-1;
    const bfloat* a0p = j.A + (size_t)ar0*K + cs*8;
    const bfloat* a1p = j.A + (size_t)ar1*K + cs*8;
    const bfloat* b0p = j.W + (size_t)br0*K + cs*8;
    const bfloat* b1p = j.W + (size_t)br1*K + cs*8;

    auto STAGE = [&](int bb, int k0){
        char* base = lds + bb*16384 + wv*1024;
        glds16(a0p + k0, base);
        glds16(a1p + k0, base + 4096);
        glds16(b0p + k0, base + 8192);
        glds16(b1p + k0, base + 12288);
    };

    const int wr = wv >> 1, wc = wv & 1;
    const int fr = ln & 15, fc = ln >> 4;
    f32x4 acc[2][2] = {};

    auto COMP = [&](int bb){
        char* bA = lds + bb*16384;
        char* bB = bA + 8192;
        int ra0 = wr*32 + fr, ra1 = ra0 + 16;
        int rb0 = wc*32 + fr, rb1 = rb0 + 16;
        #pragma unroll
        for (int kk = 0; kk < 2; ++kk){
            int ch = kk*4 + fc;
            bfx8 a0 = *(const bfx8*)(bA + ra0*128 + ((ch ^ (ra0&7))<<4));
            bfx8 a1 = *(const bfx8*)(bA + ra1*128 + ((ch ^ (ra1&7))<<4));
            bfx8 b0 = *(const bfx8*)(bB + rb0*128 + ((ch ^ (rb0&7))<<4));
            bfx8 b1 = *(const bfx8*)(bB + rb1*128 + ((ch ^ (rb1&7))<<4));
            acc[0][0] = __builtin_amdgcn_mfma_f32_16x16x32_bf16(a0,b0,acc[0][0],0,0,0);
            acc[0][1] = __builtin_amdgcn_mfma_f32_16x16x32_bf16(a0,b1,acc[0][1],0,0,0);
            acc[1][0] = __builtin_amdgcn_mfma_f32_16x16x32_bf16(a1,b0,acc[1][0],0,0,0);
            acc[1][1] = __builtin_amdgcn_mfma_f32_16x16x32_bf16(a1,b1,acc[1][1],0,0,0);
        }
    };

    const int nt = K >> 6;
    for (int s = 0; s < 3 && s < nt; ++s) STAGE(s, s << 6);
    for (int t = 0; t < nt; ++t){
        int rem = nt - 1 - t;
        if (rem >= 2)      VMWAIT(8);
        else if (rem == 1) VMWAIT(4);
        else               VMWAIT(0);
        __builtin_amdgcn_sched_barrier(0);
        __builtin_amdgcn_s_barrier();
        if (t + 3 < nt) STAGE((t+3) & 3, (t+3) << 6);
        COMP(t & 3);
    }

    const int er = (ln >> 4) * 4;
    const int ec = ln & 15;

    if (epi == 2){
        __syncthreads();
        float* ut = (float*)lds;
        #pragma unroll
        for (int i = 0; i < 2; ++i)
        #pragma unroll
        for (int jj = 0; jj < 2; ++jj)
        #pragma unroll
        for (int rr = 0; rr < 4; ++rr){
            int ml = wr*32 + i*16 + er + rr;
            int nl = wc*32 + jj*16 + ec;
            ut[ml*65 + nl] = acc[i][jj][rr] + j.bias[bn + nl];
        }
        __syncthreads();
        int rrow = tid >> 2, c0 = (tid & 3) * 16;
        int bt4 = rrow & ~3, lv = rrow & 3;
        int m = bm + rrow;
        float g[16];
        #pragma unroll
        for (int c = 0; c < 16; ++c){
            int n = bn + c0 + c;
            float a = j.cb[n];
            #pragma unroll
            for (int kh = 0; kh < 3; ++kh){
                int hh = lv + kh - 1;
                if (hh >= 0 && hh < 4)
                    a += ut[(bt4 + hh)*65 + c0 + c] * j.cw[(n*3 + kh)*3 + 1];
            }
            g[c] = gelu_tanh(a);
        }
        union { ushort u[8]; uint4 qv; } pk;
        #pragma unroll
        for (int h = 0; h < 2; ++h){
            #pragma unroll
            for (int t = 0; t < 8; ++t) pk.u[t] = bfbits(g[h*8 + t]);
            *(uint4*)(j.vb + (size_t)m*512 + bn + c0 + h*8) = pk.qv;
        }
        return;
    }

    #pragma unroll
    for (int i = 0; i < 2; ++i)
    #pragma unroll
    for (int jj = 0; jj < 2; ++jj)
    #pragma unroll
    for (int rr = 0; rr < 4; ++rr){
        int m = bm + wr*32 + i*16 + er + rr;
        int n = bn + wc*32 + jj*16 + ec;
        if (m >= M || n >= N) continue;
        float v = acc[i][jj][rr];
        if (j.bias) v += j.bias[n];
        if (epi == 1) v = gelu_tanh(v);
        if (j.res1) v += j.res1[(size_t)m*N + n];
        if (j.res2) v += j.res2[(size_t)m*N + n];
        if (epi == 3){
            int k2 = n >= 136;
            int cc = n - (k2 ? 136 : 0);
            j.Cf[((size_t)(k2*1024 + m))*136 + cc] = v;
        } else {
            if (j.Cf) j.Cf[(size_t)m*N + n] = v;
            if (j.Cb) j.Cb[(size_t)m*N + n] = __float2bfloat16(v);
        }
    }
}

// ---------------- fused selective scan + combine + LN (bf16 x input) ---------
// L=4 closed form: y_l[d] = D*x_l[d] + sum_{l'<=l} w(l,l')*dt_{l'}*S[l][l']*x_{l'}[d]
// with S[l][l'] = B_{l'}.C_l (shared across the 8 nh heads of a (bt,k)).
__global__ __launch_bounds__(256) void scan_fused_kernel(
    const float* __restrict__ xdbl,   // [2][4][1024][136]
    const bfloat* __restrict__ vb,    // [2][1024][512] bf16 (fwd layout)
    const float* __restrict__ dt_bias,// + ibase*32 pre-offset
    const float* __restrict__ A_log,
    const float* __restrict__ Dp,
    const float* __restrict__ von_w, const float* __restrict__ von_b,
    int ibase, bfloat* __restrict__ outb)
{
    __shared__ float yb[4][4][512];   // [k][l][d] 32KB
    int blk = blockIdx.x;
    int p = blk >> 8, bt = blk & 255;
    int k = threadIdx.x >> 6, lane = threadIdx.x & 63;

    const float* xd = xdbl + (size_t)p*XDBL_P + (size_t)(k*1024 + bt*4)*136;

    float bb[4], cc[4];
    #pragma unroll
    for (int l = 0; l < 4; ++l){
        bb[l] = xd[l*136 + 8 + lane];
        cc[l] = xd[l*136 + 72 + lane];
    }

    int sl = (lane & 31) >> 3, snh = lane & 7;
    float Aval = -expf(A_log[p*32 + k*8 + snh]);
    float draw = xd[sl*136 + snh] + dt_bias[p*32 + k*8 + snh];
    float dtv = fmaxf(draw, 0.f) + log1pf(expf(-fabsf(draw)));
    float dAv = expf(dtv * Aval);

    float s[16];
    #pragma unroll
    for (int l = 0; l < 4; ++l)
    #pragma unroll
    for (int jj = 0; jj < 4; ++jj)
        s[l*4+jj] = cc[l]*bb[jj];
    #pragma unroll
    for (int off = 32; off > 0; off >>= 1)
        #pragma unroll
        for (int i = 0; i < 16; ++i)
            s[i] += __shfl_xor(s[i], off, 64);

    float x[4][8];
    #pragma unroll
    for (int lp = 0; lp < 4; ++lp){
        int row = bt*4 + ((k < 2) ? lp : 3 - lp);
        const bfloat* xr = vb + (size_t)p*SEQ + (size_t)row*512 + lane;
        #pragma unroll
        for (int nh = 0; nh < 8; ++nh) x[lp][nh] = __bfloat162float(xr[nh*64]);
    }

    #pragma unroll
    for (int nh = 0; nh < 8; ++nh){
        float dtl[4], dal[4];
        #pragma unroll
        for (int l = 0; l < 4; ++l){
            dtl[l] = __shfl(dtv, l*8 + nh, 64);
            dal[l] = __shfl(dAv, l*8 + nh, 64);
        }
        float Dv = Dp[p*32 + k*8 + nh];
        float coef[4] = {0.f, 0.f, 0.f, 0.f};
        #pragma unroll
        for (int l = 0; l < 4; ++l){
            #pragma unroll
            for (int jj = 0; jj < 4; ++jj) coef[jj] *= dal[l];
            coef[l] = dtl[l];
            float y = Dv * x[l][nh];
            #pragma unroll
            for (int jj = 0; jj <= l; ++jj) y += coef[jj]*s[l*4+jj]*x[jj][nh];
            yb[k][l][nh*64 + lane] = y;
        }
    }
    __syncthreads();

    int l = k, rl = 3 - k;
    int base = lane*8;
    float vv[8];
    #pragma unroll
    for (int t = 0; t < 8; ++t)
        vv[t] = yb[0][l][base+t] + yb[1][l][base+t]
              + yb[2][rl][base+t] + yb[3][rl][base+t];
    float mean, rstd;
    ln_stats(vv, mean, rstd);
    const float* w = von_w + (ibase+p)*512;
    const float* bv = von_b + (ibase+p)*512;
    union { ushort u[8]; uint4 qv; } pk;
    #pragma unroll
    for (int t = 0; t < 8; ++t)
        pk.u[t] = bfbits((vv[t]-mean)*rstd*w[base+t] + bv[base+t]);
    *(uint4*)(outb + (size_t)p*SEQ + (size_t)(bt*4 + l)*512 + base) = pk.qv;
}

extern "C" void kernel_launch(void* const* d_in, const int* in_sizes, int n_in,
                              void* d_out, int out_size, void* d_ws, size_t ws_size,
                              hipStream_t stream)
{
    const float* style   = (const float*)d_in[0];
    const float* content = (const float*)d_in[2];
    const float* pos_s   = (const float*)d_in[4];
    const float* newps_w = (const float*)d_in[5];
    const float* newps_b = (const float*)d_in[6];
    const float* vln_w   = (const float*)d_in[7];
    const float* vln_b   = (const float*)d_in[8];
    const float* vin_b   = (const float*)d_in[10];
    const float* vconv_w = (const float*)d_in[11];
    const float* vconv_b = (const float*)d_in[12];
    const float* vdt_bias= (const float*)d_in[14];
    const float* vA_log  = (const float*)d_in[15];
    const float* vD      = (const float*)d_in[16];
    const float* von_w   = (const float*)d_in[17];
    const float* von_b   = (const float*)d_in[18];
    const float* vout_b  = (const float*)d_in[20];
    const float* lin1_b  = (const float*)d_in[22];
    const float* lin2_b  = (const float*)d_in[24];
    const float* dn1_w   = (const float*)d_in[25];
    const float* dn1_b   = (const float*)d_in[26];
    const float* dn2_w   = (const float*)d_in[27];
    const float* dn2_b   = (const float*)d_in[28];
    const float* dn3_w   = (const float*)d_in[29];
    const float* dn3_b   = (const float*)d_in[30];
    const float* decn_w  = (const float*)d_in[31];
    const float* decn_b  = (const float*)d_in[32];

    float* out = (float*)d_out;
    float* ws  = (float*)d_ws;

    // ---- fp32 region ----
    float* s_seq  = ws + (size_t) 0*SEQ;
    float* c_seq  = ws + (size_t) 1*SEQ;
    float* ps_seq = ws + (size_t) 2*SEQ;
    float* pc_seq = ws + (size_t) 3*SEQ;
    float* s_enc  = ws + (size_t) 4*SEQ;
    float* c_enc  = ws + (size_t) 5*SEQ;
    float* t1     = ws + (size_t) 6*SEQ;
    float* t2     = ws + (size_t) 7*SEQ;
    float* tgt    = ws + (size_t) 8*SEQ;
    float* ffnout = ws + (size_t) 9*SEQ;
    float* xdbl   = ws + (size_t)10*SEQ;   // [2][557056] spans 10-12
    float* pc18T  = ws + (size_t)13*SEQ;   // 663552 floats (13-14)

    // ---- bf16 region at 15 SEQ floats ----
    bfloat* wb = (bfloat*)(ws + (size_t)15*SEQ);
    bfloat* wb_vin    = wb;
    bfloat* wb_xproj  = wb + 1048576;
    bfloat* wb_vout   = wb + 2162688;
    bfloat* wb_lin1   = wb + 3211264;
    bfloat* wb_lin2   = wb + 4259840;
    bfloat* wb_newps  = wb + 5308416;
    bfloat* xn_bf     = wb + 5570560;               // [2][SEQ] (also yln pair)
    bfloat* vbuf_bf   = xn_bf   + (size_t)2*SEQ;    // [2][SEQ]
    bfloat* tgt_bf    = vbuf_bf + (size_t)2*SEQ;    // SEQ
    bfloat* ffn_bf    = tgt_bf  + (size_t)SEQ;      // 1024*2048
    bfloat* pooled_bf = ffn_bf;                     // pre-VSS only

    auto launch_gemm = [&](GJob* jobs, int nz, int M, int N, int K, int epi){
        int nbm = (M + 63)/64, nbn = (N + 63)/64;
        dim3 g(nbm*nbn, 1, nz);
        gemm3_kernel<<<g, 256, 0, stream>>>(jobs[0], jobs[nz>1?1:0],
                                            jobs[nz>2?2:0], jobs[nz>3?3:0],
                                            M, N, K, nbn, epi);
    };

    GJob Z = {};

    auto vss_pair = [&](const float* xa, const float* x2a,
                        const float* xb, const float* x2b,
                        int ibase, float* oa, float* ob){
        ln_vss_pair_kernel<<<512, 256, 0, stream>>>(xa, x2a, xb, x2b,
                                                    vln_w, vln_b, ibase, xn_bf);
        GJob jv[2];
        for (int p = 0; p < 2; ++p){
            int i = ibase + p;
            jv[p] = Z;
            jv[p].A = xn_bf + (size_t)p*SEQ;
            jv[p].W = wb_vin + (size_t)i*262144;
            jv[p].bias = vin_b + i*512;
            jv[p].cw = vconv_w + (size_t)i*4608;
            jv[p].cb = vconv_b + i*512;
            jv[p].vb = vbuf_bf + (size_t)p*SEQ;
        }
        launch_gemm(jv, 2, MROWS, 512, 512, 2);

        GJob jx[4];
        for (int zz = 0; zz < 4; ++zz){
            int p = zz >> 1, rev = zz & 1, i = ibase + p;
            jx[zz] = Z;
            jx[zz].A = vbuf_bf + (size_t)p*SEQ;
            jx[zz].arev = rev;
            jx[zz].W = wb_xproj + (size_t)i*278528 + (size_t)rev*272*512;
            jx[zz].Cf = xdbl + (size_t)p*XDBL_P + (size_t)rev*278528;
        }
        launch_gemm(jx, 4, MROWS, 272, 512, 3);

        scan_fused_kernel<<<512, 256, 0, stream>>>(xdbl, vbuf_bf,
                                                   vdt_bias + ibase*32,
                                                   vA_log + ibase*32,
                                                   vD + ibase*32,
                                                   von_w, von_b, ibase, xn_bf);

        GJob jo[2];
        const float* r1[2] = {xa, xb};
        const float* r2[2] = {x2a, x2b};
        float* oo[2] = {oa, ob};
        for (int p = 0; p < 2; ++p){
            int i = ibase + p;
            jo[p] = Z;
            jo[p].A = xn_bf + (size_t)p*SEQ;
            jo[p].W = wb_vout + (size_t)i*262144;
            jo[p].bias = vout_b + i*512;
            jo[p].res1 = r1[p];
            jo[p].res2 = r2[p];
            jo[p].Cf = oo[p];
        }
        launch_gemm(jo, 2, MROWS, 512, 512, 0);
    };

    // ---- prep: cvt_w + to_seq3 + pool ----
    CvtArgs ca;
    ca.s[0]=(const float*)d_in[9];  ca.d[0]=wb_vin;
    ca.s[1]=(const float*)d_in[13]; ca.d[1]=wb_xproj;
    ca.s[2]=(const float*)d_in[19]; ca.d[2]=wb_vout;
    ca.s[3]=(const float*)d_in[21]; ca.d[3]=wb_lin1;
    ca.s[4]=(const float*)d_in[23]; ca.d[4]=wb_lin2;
    ca.s[5]=newps_w;                ca.d[5]=wb_newps;
    ca.c4[0]=262144; ca.c4[1]=540672; ca.c4[2]=802816;
    ca.c4[3]=1064960; ca.c4[4]=1327104; ca.c4[5]=1392640;
    prep_kernel<<<8272, 256, 0, stream>>>(ca, style, content, pos_s,
                                          s_seq, c_seq, ps_seq, pooled_bf);

    // ---- positional path ----
    GJob jn = Z;
    jn.A = pooled_bf; jn.W = wb_newps; jn.bias = newps_b; jn.Cf = pc18T;
    launch_gemm(&jn, 1, 1296, 512, 512, 0);
    resize_kernel<<<1024, 256, 0, stream>>>(pc18T, pc_seq);

    // ---- encoders (pair) ----
    vss_pair(s_seq, nullptr, c_seq, nullptr, 0, s_enc, c_enc);

    // ---- decoders (pair) ----
    vss_pair(c_enc, pc_seq, s_enc, ps_seq, 2, t1, t2);
    dn_pair_kernel<<<256, 256, 0, stream>>>(c_enc, t1, dn1_w, dn1_b,
                                            s_enc, t2, dn2_w, dn2_b,
                                            tgt, tgt_bf);

    // ---- FFN + tail ----
    GJob jf = Z;
    jf.A = tgt_bf; jf.W = wb_lin1; jf.bias = lin1_b; jf.Cb = ffn_bf;
    launch_gemm(&jf, 1, MROWS, 2048, 512, 1);
    GJob jg = Z;
    jg.A = ffn_bf; jg.W = wb_lin2; jg.bias = lin2_b; jg.Cf = ffnout;
    launch_gemm(&jg, 1, MROWS, 512, 2048, 0);
    ln2_out_kernel<<<256, 256, 0, stream>>>(tgt, ffnout, dn3_w, dn3_b,
                                            decn_w, decn_b, out);
}